// Round 3
// baseline (245.317 us; speedup 1.0000x reference)
//
#include <hip/hip_runtime.h>

// Problem constants
#define NB 16          // batch
#define NV 8           // vars per sample
#define HW 512         // H = W
#define PH 16          // patch h = w
#define GH 32          // grid h = w (512/16)
#define ED 128         // embed dim
#define KD 256         // 16*16 patch elems
#define MAXV 10

typedef __bf16 bf16x8 __attribute__((ext_vector_type(8)));
typedef float  f32x4  __attribute__((ext_vector_type(4)));

// ---------------------------------------------------------------------------
// v7: SINGLE-KERNEL, LDS-free, barrier-free streaming pipeline.
//
// v6 post-mortem: v4 (LDS) / v5 (nt) / v6 (cached) all ~220 us total ->
// patch_embed is HBM-bound at its floor; remaining controllable cost is the
// two-kernel structure.  pack_weights only re-layouts 1.3 MB of fp32 weight
// into bf16 fragment order, but the fragment elements are ALREADY contiguous
// in the raw layout:
//   frag j, step T, lane (lo,quad):  w[(var*128 + j*16+lo)*256 + T*32 + quad*8 + e]
//   e = 0..7  ->  two dwordx4 per frag, same shape as the A-path.
// So v7 deletes pack_weights + the 640 KB workspace round-trip + one kernel
// launch boundary, loading raw f32 weights (L2-resident, 1.3 MB < 4 MB/XCD)
// and converting to bf16 in-register (same RNE cast -> identical numerics).
//
// Per-wave schedule (no barriers, no LDS, compiler-counted vmcnt):
//   prologue: BRAW(0) issued FIRST (cold-HBM fetch overlaps A-ring fill),
//             then ALOAD(0..3)  [A 4-deep ring, 16 KB in flight/wave]
//   step KB:  cvt braw->bF | issue BRAW(KB+1) | cvt A | 16x MFMA | ALOAD(KB+4)
// Register budget: acc 64 + araw 64 + braw 64 + bF 32 + addr ~20 = ~245 < 256.
// ---------------------------------------------------------------------------
__global__ __launch_bounds__(256, 2) void patch_embed(
    const float* __restrict__ x,
    const int*   __restrict__ in_vars,
    const float* __restrict__ w,
    const float* __restrict__ bias,
    float* __restrict__ out)
{
    const int tid  = threadIdx.x;
    const int wv   = tid >> 6;
    const int lane = tid & 63;
    const int lo   = lane & 15;
    const int quad = lane >> 4;
    const int qh   = quad >> 1;
    const int qlo  = quad & 1;

    // strip id: 4 strips per block (same b,v across the block's waves)
    const int sid = blockIdx.x * 4 + wv;
    const int h   = sid & 31;
    const int v   = (sid >> 5) & 7;
    const int b   = sid >> 8;

    const int var = in_vars[v];

    const char* xstrip = (const char*)(x + (((size_t)(b * NV + v)) * HW + (size_t)h * PH) * HW);

    // per-lane A base: step kb / tile i / half hf adds kb*4096 + i*1024 + hf*16
    const char* abase = xstrip + qh * 2048 + lo * 64 + qlo * 32;

    // per-lane raw-weight base: frag j adds j*16384, step T adds T*128, half +16
    const char* bbase = (const char*)(w + (size_t)var * (ED * KD)) + lo * 1024 + quad * 32;

    f32x4  araw[4][4];   // 4-deep A ring: [stage][i*2+half]
    f32x4  braw[8][2];   // 1-deep B ring (raw f32, next step's fragments)
    f32x4  acc[2][8];

    // ---- bias folded into accumulator init (all 4 rows share bias[n]) ----
    #pragma unroll
    for (int j = 0; j < 8; ++j) {
        float bv = bias[var * ED + j * 16 + lo];
        #pragma unroll
        for (int i = 0; i < 2; ++i)
            acc[i][j] = (f32x4){bv, bv, bv, bv};
    }

    // ---- load one A stage (4 x dwordx4, cache-allocating) ----
#define ALOAD(T) { \
        _Pragma("unroll") for (int i = 0; i < 2; ++i) \
            _Pragma("unroll") for (int hf = 0; hf < 2; ++hf) \
                araw[(T) & 3][i * 2 + hf] = \
                    *(const f32x4*)(abase + (T) * 4096 + i * 1024 + hf * 16); }

    // ---- load one B k-block raw (8 frags x 2 dwordx4) from L2-resident w ---
#define BRAW(T) { \
        _Pragma("unroll") for (int j = 0; j < 8; ++j) \
            _Pragma("unroll") for (int hf = 0; hf < 2; ++hf) \
                braw[j][hf] = *(const f32x4*)(bbase + j * 16384 + (T) * 128 + hf * 16); }

    // ---- prologue: B first (overlap cold w fetch), then A 4-deep ----
    BRAW(0);
    ALOAD(0); ALOAD(1); ALOAD(2); ALOAD(3);

    // ---- K-loop: 8 steps, fully unrolled; compiler emits counted vmcnt ----
#define STEP(KB) { \
        bf16x8 bF[8]; \
        _Pragma("unroll") for (int j = 0; j < 8; ++j) { \
            f32x4 r0 = braw[j][0]; \
            f32x4 r1 = braw[j][1]; \
            bf16x8 t; \
            t[0] = (__bf16)r0.x; t[1] = (__bf16)r0.y; t[2] = (__bf16)r0.z; t[3] = (__bf16)r0.w; \
            t[4] = (__bf16)r1.x; t[5] = (__bf16)r1.y; t[6] = (__bf16)r1.z; t[7] = (__bf16)r1.w; \
            bF[j] = t; } \
        if ((KB) + 1 < 8) BRAW((KB) + 1); \
        bf16x8 aF[2]; \
        _Pragma("unroll") for (int i = 0; i < 2; ++i) { \
            f32x4 r0 = araw[(KB) & 3][i * 2 + 0]; \
            f32x4 r1 = araw[(KB) & 3][i * 2 + 1]; \
            bf16x8 t; \
            t[0] = (__bf16)r0.x; t[1] = (__bf16)r0.y; t[2] = (__bf16)r0.z; t[3] = (__bf16)r0.w; \
            t[4] = (__bf16)r1.x; t[5] = (__bf16)r1.y; t[6] = (__bf16)r1.z; t[7] = (__bf16)r1.w; \
            aF[i] = t; } \
        __builtin_amdgcn_s_setprio(1); \
        _Pragma("unroll") for (int i = 0; i < 2; ++i) \
            _Pragma("unroll") for (int j = 0; j < 8; ++j) \
                acc[i][j] = __builtin_amdgcn_mfma_f32_16x16x32_bf16(aF[i], bF[j], acc[i][j], 0, 0, 0); \
        __builtin_amdgcn_s_setprio(0); \
        if ((KB) + 4 < 8) ALOAD((KB) + 4); }

    STEP(0)
    STEP(1)
    STEP(2)
    STEP(3)
    STEP(4)
    STEP(5)
    STEP(6)
    STEP(7)

#undef STEP
#undef BRAW
#undef ALOAD

    // ---- epilogue: C/D layout col = lane&15, row = quad*4 + reg (m89) ----
    // bias already in acc; nontemporal stores (out never re-read; each store
    // instruction covers full 64 B aligned chunks -> nt is traffic-safe).
    const size_t outbase = ((size_t)(b * NV + v)) * (GH * GH) + (size_t)h * GH;
    #pragma unroll
    for (int i = 0; i < 2; ++i) {
        #pragma unroll
        for (int r = 0; r < 4; ++r) {
            int m = i * 16 + quad * 4 + r;   // patch index within strip
            #pragma unroll
            for (int j = 0; j < 8; ++j) {
                __builtin_nontemporal_store(acc[i][j][r],
                    &out[(outbase + m) * ED + j * 16 + lo]);
            }
        }
    }
}

extern "C" void kernel_launch(void* const* d_in, const int* in_sizes, int n_in,
                              void* d_out, int out_size, void* d_ws, size_t ws_size,
                              hipStream_t stream) {
    const float* x       = (const float*)d_in[0];
    const int*   in_vars = (const int*)d_in[1];
    const float* w       = (const float*)d_in[2];
    const float* bias    = (const float*)d_in[3];
    float*       out     = (float*)d_out;
    (void)d_ws; (void)ws_size;

    hipLaunchKernelGGL(patch_embed, dim3(NB * NV * GH / 4), dim3(256), 0, stream,
                       x, in_vars, w, bias, out);
}

// Round 4
// 219.981 us; speedup vs baseline: 1.1152x; 1.1152x over previous
//
#include <hip/hip_runtime.h>

// Problem constants
#define NB 16          // batch
#define NV 8           // vars per sample
#define HW 512         // H = W
#define PH 16          // patch h = w
#define GH 32          // grid h = w (512/16)
#define ED 128         // embed dim
#define KD 256         // 16*16 patch elems
#define MAXV 10

typedef __bf16 bf16x8 __attribute__((ext_vector_type(8)));
typedef float  f32x4  __attribute__((ext_vector_type(4)));

// ---------------------------------------------------------------------------
// Pack fp32 weights -> bf16 in B-fragment order:
//   packed[var*32768 + kb*4096 + n*32 + t], k = kb*32 + t, t = quad*8 + j
// v7 post-mortem: this kernel is NOT dead weight.  Reading raw w in fragment
// order puts quad-lanes 1 KB apart (64-line gather per dwordx4, 16x request
// amplification) and costs 64 extra VGPRs -> patch_embed 50 -> 95 us.  The
// 4 us pack buys perfectly coalesced, L2-resident B loads.  Keep it.
// ---------------------------------------------------------------------------
__global__ __launch_bounds__(256) void pack_weights(const float* __restrict__ w,
                                                    __bf16* __restrict__ packed) {
    int tid = blockIdx.x * 256 + threadIdx.x;
    if (tid >= MAXV * ED * KD) return;
    int t   = tid & 31;
    int n   = (tid >> 5) & 127;
    int kb  = (tid >> 12) & 7;
    int var = tid >> 15;
    int k   = kb * 32 + t;
    float f = w[(var * ED + n) * KD + k];
    packed[tid] = (__bf16)f;
}

// ---------------------------------------------------------------------------
// v8 = v6 (best-known-good, 220.3us ~ v4's 219.7): LDS-free, barrier-free
// streaming pipeline with CACHED A-loads and packed bf16 B.
//
// One WAVE = one strip (32 patches x 128 emb).  Each lane's A fragment is
// 32 B contiguous in global memory:
//     xstrip + (2kb+qh)*2048 + (i*16+lo)*64 + qlo*32      (two dwordx4)
// A raw-f32 data rides a 4-deep register ring (16 KB in flight per wave);
// B fragments ride a 2-deep register ring from L2-resident packed weights
// (fully coalesced: a wave's BLOAD frag covers 1 KB contiguous).
// Compiler emits exact counted vmcnt waits; no barriers, no LDS.
//
// Measured invariants (rounds 0-3): total ~= 2x80us harness poison fills
// (uncontrollable, persist even with d_ws unused) + pack ~4us + patch ~50us.
// patch-internal variants (LDS/nt/cached) all within +-3us of 220.
// ---------------------------------------------------------------------------
__global__ __launch_bounds__(256, 2) void patch_embed(
    const float* __restrict__ x,
    const int*   __restrict__ in_vars,
    const __bf16* __restrict__ wpacked,
    const float* __restrict__ bias,
    float* __restrict__ out)
{
    const int tid  = threadIdx.x;
    const int wv   = tid >> 6;
    const int lane = tid & 63;
    const int lo   = lane & 15;
    const int quad = lane >> 4;
    const int qh   = quad >> 1;
    const int qlo  = quad & 1;

    // strip id: 4 strips per block
    const int sid = blockIdx.x * 4 + wv;
    const int h   = sid & 31;
    const int v   = (sid >> 5) & 7;
    const int b   = sid >> 8;

    const int var = in_vars[v];

    const char* xstrip = (const char*)(x + (((size_t)(b * NV + v)) * HW + (size_t)h * PH) * HW);
    const __bf16* wbase = wpacked + (size_t)var * (ED * KD);

    // per-lane A base: step kb / tile i / half hf adds kb*4096 + i*1024 + hf*16
    const char* abase = xstrip + qh * 2048 + lo * 64 + qlo * 32;

    f32x4  araw[4][4];   // 4-deep A ring: [stage][i*2+half]
    bf16x8 bF[2][8];     // 2-deep B ring
    f32x4  acc[2][8];

    // ---- bias folded into accumulator init (all 4 rows share bias[n]) ----
    #pragma unroll
    for (int j = 0; j < 8; ++j) {
        float bv = bias[var * ED + j * 16 + lo];
        #pragma unroll
        for (int i = 0; i < 2; ++i)
            acc[i][j] = (f32x4){bv, bv, bv, bv};
    }

    // ---- load one A stage (4 x dwordx4, cache-allocating) ----
#define ALOAD(T) { \
        _Pragma("unroll") for (int i = 0; i < 2; ++i) \
            _Pragma("unroll") for (int hf = 0; hf < 2; ++hf) \
                araw[(T) & 3][i * 2 + hf] = \
                    *(const f32x4*)(abase + (T) * 4096 + i * 1024 + hf * 16); }

    // ---- load one B k-block (8 frags, 16 B each) from L2-resident weights --
#define BLOAD(T) { \
        _Pragma("unroll") for (int j = 0; j < 8; ++j) \
            bF[(T) & 1][j] = *(const bf16x8*)&wbase[(T) * 4096 + (j * 16 + lo) * 32 + quad * 8]; }

    // ---- prologue: A 4-deep, B 2-deep ----
    ALOAD(0); BLOAD(0); ALOAD(1); BLOAD(1); ALOAD(2); ALOAD(3);

    // ---- K-loop: 8 steps, fully unrolled; compiler emits counted vmcnt ----
#define STEP(KB) { \
        bf16x8 aF[2]; \
        _Pragma("unroll") for (int i = 0; i < 2; ++i) { \
            f32x4 r0 = araw[(KB) & 3][i * 2 + 0]; \
            f32x4 r1 = araw[(KB) & 3][i * 2 + 1]; \
            bf16x8 t; \
            t[0] = (__bf16)r0.x; t[1] = (__bf16)r0.y; t[2] = (__bf16)r0.z; t[3] = (__bf16)r0.w; \
            t[4] = (__bf16)r1.x; t[5] = (__bf16)r1.y; t[6] = (__bf16)r1.z; t[7] = (__bf16)r1.w; \
            aF[i] = t; } \
        __builtin_amdgcn_s_setprio(1); \
        _Pragma("unroll") for (int i = 0; i < 2; ++i) \
            _Pragma("unroll") for (int j = 0; j < 8; ++j) \
                acc[i][j] = __builtin_amdgcn_mfma_f32_16x16x32_bf16(aF[i], bF[(KB) & 1][j], acc[i][j], 0, 0, 0); \
        __builtin_amdgcn_s_setprio(0); \
        if ((KB) + 4 < 8) ALOAD((KB) + 4); \
        if ((KB) + 2 < 8) BLOAD((KB) + 2); }

    STEP(0)
    STEP(1)
    STEP(2)
    STEP(3)
    STEP(4)
    STEP(5)
    STEP(6)
    STEP(7)

#undef STEP
#undef BLOAD
#undef ALOAD

    // ---- epilogue: C/D layout col = lane&15, row = quad*4 + reg (m89) ----
    // bias already in acc; nontemporal stores (out never re-read; each store
    // instruction covers full 64 B aligned chunks -> nt is traffic-safe).
    const size_t outbase = ((size_t)(b * NV + v)) * (GH * GH) + (size_t)h * GH;
    #pragma unroll
    for (int i = 0; i < 2; ++i) {
        #pragma unroll
        for (int r = 0; r < 4; ++r) {
            int m = i * 16 + quad * 4 + r;   // patch index within strip
            #pragma unroll
            for (int j = 0; j < 8; ++j) {
                __builtin_nontemporal_store(acc[i][j][r],
                    &out[(outbase + m) * ED + j * 16 + lo]);
            }
        }
    }
}

extern "C" void kernel_launch(void* const* d_in, const int* in_sizes, int n_in,
                              void* d_out, int out_size, void* d_ws, size_t ws_size,
                              hipStream_t stream) {
    const float* x       = (const float*)d_in[0];
    const int*   in_vars = (const int*)d_in[1];
    const float* w       = (const float*)d_in[2];
    const float* bias    = (const float*)d_in[3];
    float*       out     = (float*)d_out;
    __bf16*      wpacked = (__bf16*)d_ws;   // 655,360 B needed

    hipLaunchKernelGGL(pack_weights, dim3((MAXV * ED * KD + 255) / 256), dim3(256), 0, stream,
                       w, wpacked);
    hipLaunchKernelGGL(patch_embed, dim3(NB * NV * GH / 4), dim3(256), 0, stream,
                       x, in_vars, wpacked, bias, out);
}